// Round 10
// baseline (588.185 us; speedup 1.0000x reference)
//
#include <hip/hip_runtime.h>
#include <hip/hip_bf16.h>

#define H_DIM 2048
#define N_HEADS 16
#define HEAD_DIM 128
#define BATCH 2
#define SEQ 2048

typedef __bf16 bf16_t;
typedef __bf16 bf16x8 __attribute__((ext_vector_type(8)));
typedef float f32x4 __attribute__((ext_vector_type(4)));
typedef unsigned long long u64_t;

#define MFMA16(a, b, c) __builtin_amdgcn_mfma_f32_16x16x32_bf16((a), (b), (c), 0, 0, 0)

// async global->LDS, 16 B per lane. LDS side must be uniform-base + lane*16.
#define GLOAD16(gp, lp) __builtin_amdgcn_global_load_lds( \
    (const __attribute__((address_space(1))) void*)(gp),  \
    (__attribute__((address_space(3))) void*)(lp), 16, 0, 0)

// flags[0] = inputs stored as bf16 (1) or fp32 (0); flags[1] = mask all-ones
__global__ __launch_bounds__(256) void detect_kernel(const unsigned int* __restrict__ X,
                                                     int* __restrict__ flags) {
    __shared__ int cnt[256];
    int t = threadIdx.x;
    int c = 0;
    for (int i = 0; i < 16; i++) {
        unsigned w  = X[t * 16 + i];
        unsigned lo = w & 0xFFFFu;
        unsigned e  = (lo >> 7) & 0xFFu;
        if (lo == 0u || (e >= 100u && e <= 141u)) c++;
    }
    cnt[t] = c;
    __syncthreads();
    for (int s = 128; s > 0; s >>= 1) {
        if (t < s) cnt[t] += cnt[t + s];
        __syncthreads();
    }
    if (t == 0) { flags[0] = (cnt[0] >= 2048) ? 1 : 0; flags[1] = 1; }
}

__device__ inline bf16x8 load8(const void* __restrict__ p, size_t idx, int isbf16) {
    if (isbf16) {
        return *(const bf16x8*)((const bf16_t*)p + idx);
    } else {
        const float* f = (const float*)p + idx;
        float4 a = *(const float4*)f;
        float4 b = *(const float4*)(f + 4);
        bf16x8 r;
        r[0] = (bf16_t)a.x; r[1] = (bf16_t)a.y; r[2] = (bf16_t)a.z; r[3] = (bf16_t)a.w;
        r[4] = (bf16_t)b.x; r[5] = (bf16_t)b.y; r[6] = (bf16_t)b.z; r[7] = (bf16_t)b.w;
        return r;
    }
}

__device__ inline float readf(const void* __restrict__ p, int idx, int isbf16) {
    return isbf16 ? (float)((const bf16_t*)p)[idx] : ((const float*)p)[idx];
}

// X -> Xb (bf16) + mask all-ones check, fused (same element count: 8388608).
__global__ __launch_bounds__(256) void convert_mask_kernel(
    const void* __restrict__ X, bf16_t* __restrict__ Xb,
    const int* __restrict__ mask, int* __restrict__ flags)
{
    const int isbf16 = flags[0];
    size_t i = ((size_t)blockIdx.x * 256 + threadIdx.x) * 8;
    bf16x8 v = load8(X, i, isbf16);
    *(bf16x8*)(Xb + i) = v;

    const int4* p = (const int4*)(mask + i);
    int4 a = p[0], b = p[1];
    int all = (a.x != 0) & (a.y != 0) & (a.z != 0) & (a.w != 0) &
              (b.x != 0) & (b.y != 0) & (b.z != 0) & (b.w != 0);
    if (!all) atomicAnd(&flags[1], 0);
}

// Wt[z][n][k] = W_z[k][n], bf16 output. grid (32,32,4), 64x64 tiles.
__global__ __launch_bounds__(256) void transpose_kernel(
    const void* __restrict__ W0, const void* __restrict__ W1,
    const void* __restrict__ W2, const void* __restrict__ W3,
    bf16_t* __restrict__ Wts, const int* __restrict__ flags)
{
    const int isbf16 = flags[0];
    const int z = blockIdx.z;
    const void* W = (z == 0) ? W0 : (z == 1) ? W1 : (z == 2) ? W2 : W3;
    bf16_t* out = Wts + (size_t)z * H_DIM * H_DIM;

    __shared__ __attribute__((aligned(16))) bf16_t Ts[64][72];
    const int tid = threadIdx.x;
    const int n0 = blockIdx.x * 64;
    const int k0 = blockIdx.y * 64;

    #pragma unroll
    for (int j = 0; j < 2; j++) {
        int idx = j * 2048 + tid * 8;
        int r = idx >> 6, c = idx & 63;
        bf16x8 v = load8(W, (size_t)(k0 + r) * H_DIM + n0 + c, isbf16);
        *(bf16x8*)(&Ts[r][c]) = v;
    }
    __syncthreads();
    const int wr = tid & 63;
    const int wcg = (tid >> 6) * 8;
    #pragma unroll
    for (int j = 0; j < 2; j++) {
        int wc = wcg + j * 32;
        bf16x8 o;
        #pragma unroll
        for (int u = 0; u < 8; u++) o[u] = Ts[wc + u][wr];
        *(bf16x8*)(&out[(size_t)(n0 + wr) * H_DIM + k0 + wc]) = o;
    }
}

// 128x128 GEMM, m97-style simple 2-barrier single-buffer (16 KB LDS -> ~6
// blocks/CU, grid 1536 fully co-resident, zero tail; m114 cross-wave overlap
// hides the barrier drain). XCD-swizzled 1-D grid.
// z=0,1: scatter [B,H,S,D] (Q,K). z=2: scatter V^T [B,H,D,S].
__global__ __launch_bounds__(256) void gemm_qkv_kernel(
    const bf16_t* __restrict__ A, const bf16_t* __restrict__ Wts,
    const void* __restrict__ b0, const void* __restrict__ b1, const void* __restrict__ b2,
    bf16_t* __restrict__ qws, bf16_t* __restrict__ kws, bf16_t* __restrict__ vtws,
    const int* __restrict__ flags)
{
    const int isbf16 = flags[0];
    const int L    = blockIdx.x;
    const int xcd  = L & 7;
    const int j    = L >> 3;              // 0..191
    const int c    = xcd * 6 + (j % 6);   // 0..47 = z*16 + ncol
    const int mrow = j / 6;               // 0..31
    const int z    = c >> 4;
    const int m0   = mrow * 128;
    const int n0   = (c & 15) * 128;

    const bf16_t* Wt = Wts + (size_t)z * H_DIM * H_DIM;
    const void* bias = (z == 0) ? b0 : (z == 1) ? b1 : b2;
    bf16_t* dst = (z == 0) ? qws : (z == 1) ? kws : vtws;

    __shared__ __attribute__((aligned(16))) bf16_t As[4][128][8];  // 8 KB
    __shared__ __attribute__((aligned(16))) bf16_t Bs[4][128][8];  // 8 KB

    const int tid  = threadIdx.x;
    const int lane = tid & 63;
    const int wid  = tid >> 6;
    const int quad = lane >> 4;
    const int l16  = lane & 15;
    const int wm   = (wid >> 1) * 64;
    const int wn   = (wid & 1) * 64;

    f32x4 acc[4][4] = {};

    for (int k0 = 0; k0 < H_DIM; k0 += 32) {
        #pragma unroll
        for (int jj = 0; jj < 2; jj++) {
            int slot = jj * 256 + tid;
            int k8 = slot >> 7, row = slot & 127;
            GLOAD16(A  + (size_t)(m0 + row) * H_DIM + k0 + k8 * 8, (bf16_t*)As + slot * 8);
            GLOAD16(Wt + (size_t)(n0 + row) * H_DIM + k0 + k8 * 8, (bf16_t*)Bs + slot * 8);
        }
        __syncthreads();
        bf16x8 af[4], bfr[4];
        #pragma unroll
        for (int i = 0; i < 4; i++) {
            af[i]  = *(const bf16x8*)(&As[quad][wm + i * 16 + l16][0]);
            bfr[i] = *(const bf16x8*)(&Bs[quad][wn + i * 16 + l16][0]);
        }
        #pragma unroll
        for (int mi = 0; mi < 4; mi++)
            #pragma unroll
            for (int ni = 0; ni < 4; ni++)
                acc[mi][ni] = MFMA16(af[mi], bfr[ni], acc[mi][ni]);
        __syncthreads();
    }

    // C/D layout: col = lane&15, row = quad*4 + reg
    #pragma unroll
    for (int ni = 0; ni < 4; ni++) {
        int col = n0 + wn + ni * 16 + l16;
        int h = col >> 7, d = col & (HEAD_DIM - 1);
        float bv = readf(bias, col, isbf16);
        #pragma unroll
        for (int mi = 0; mi < 4; mi++) {
            int row0 = m0 + wm + mi * 16 + quad * 4;
            int b = row0 >> 11;
            if (z < 2) {
                #pragma unroll
                for (int r = 0; r < 4; r++) {
                    int s = (row0 + r) & (SEQ - 1);
                    dst[((size_t)(b * N_HEADS + h) * SEQ + s) * HEAD_DIM + d] =
                        (bf16_t)(acc[mi][ni][r] + bv);
                }
            } else {
                int s0 = row0 & (SEQ - 1);
                bf16_t o[4];
                #pragma unroll
                for (int r = 0; r < 4; r++) o[r] = (bf16_t)(acc[mi][ni][r] + bv);
                *(u64_t*)(&dst[((size_t)(b * N_HEADS + h) * HEAD_DIM + d) * SEQ + s0]) =
                    *(u64_t*)o;
            }
        }
    }
}

// out-projection, same m97-simple structure. grid(512), fully resident.
__global__ __launch_bounds__(256) void gemm_out_kernel(
    const bf16_t* __restrict__ A, const bf16_t* __restrict__ Wt,
    const void* __restrict__ bias, void* __restrict__ C,
    const int* __restrict__ flags)
{
    const int isbf16 = flags[0];
    const int L    = blockIdx.x;
    const int xcd  = L & 7;
    const int j    = L >> 3;              // 0..63
    const int m0   = (j >> 1) * 128;
    const int n0   = (xcd * 2 + (j & 1)) * 128;

    __shared__ __attribute__((aligned(16))) bf16_t As[4][128][8];
    __shared__ __attribute__((aligned(16))) bf16_t Bs[4][128][8];

    const int tid  = threadIdx.x;
    const int lane = tid & 63;
    const int wid  = tid >> 6;
    const int quad = lane >> 4;
    const int l16  = lane & 15;
    const int wm   = (wid >> 1) * 64;
    const int wn   = (wid & 1) * 64;

    f32x4 acc[4][4] = {};

    for (int k0 = 0; k0 < H_DIM; k0 += 32) {
        #pragma unroll
        for (int jj = 0; jj < 2; jj++) {
            int slot = jj * 256 + tid;
            int k8 = slot >> 7, row = slot & 127;
            GLOAD16(A  + (size_t)(m0 + row) * H_DIM + k0 + k8 * 8, (bf16_t*)As + slot * 8);
            GLOAD16(Wt + (size_t)(n0 + row) * H_DIM + k0 + k8 * 8, (bf16_t*)Bs + slot * 8);
        }
        __syncthreads();
        bf16x8 af[4], bfr[4];
        #pragma unroll
        for (int i = 0; i < 4; i++) {
            af[i]  = *(const bf16x8*)(&As[quad][wm + i * 16 + l16][0]);
            bfr[i] = *(const bf16x8*)(&Bs[quad][wn + i * 16 + l16][0]);
        }
        #pragma unroll
        for (int mi = 0; mi < 4; mi++)
            #pragma unroll
            for (int ni = 0; ni < 4; ni++)
                acc[mi][ni] = MFMA16(af[mi], bfr[ni], acc[mi][ni]);
        __syncthreads();
    }

    #pragma unroll
    for (int ni = 0; ni < 4; ni++) {
        int col = n0 + wn + ni * 16 + l16;
        float bv = readf(bias, col, isbf16);
        #pragma unroll
        for (int mi = 0; mi < 4; mi++) {
            int row0 = m0 + wm + mi * 16 + quad * 4;
            #pragma unroll
            for (int r = 0; r < 4; r++) {
                float v = acc[mi][ni][r] + bv;
                if (isbf16) ((bf16_t*)C)[(size_t)(row0 + r) * H_DIM + col] = (bf16_t)v;
                else        ((float*)C)[(size_t)(row0 + r) * H_DIM + col]  = v;
            }
        }
    }
}

// Flash attention, dual-Q, fixed-offset softmax. PV computed as
// O^T = V^T(A-op) x P(B-op): identical LDS bytes/addressing (operand swap only),
// but C-layout flips to col=q,row=d -> 8-B packed ctx stores + scalar l per lane.
__global__ __launch_bounds__(256, 2) void attn_kernel(
    const bf16_t* __restrict__ Q, const bf16_t* __restrict__ K,
    const bf16_t* __restrict__ Vt, const int* __restrict__ mask,
    const int* __restrict__ flags, bf16_t* __restrict__ ctx)
{
    __shared__ __attribute__((aligned(16))) bf16_t Ks[2][16][64][8];  // 32 KB
    __shared__ __attribute__((aligned(16))) bf16_t Vs[2][8][128][8];  // 32 KB
    __shared__ __attribute__((aligned(16))) bf16_t Pl[4][16][72];     // 9 KB, per-wave

    const int tid  = threadIdx.x;
    const int lane = tid & 63;
    const int wid  = tid >> 6;
    const int quad = lane >> 4;
    const int l16  = lane & 15;

    const int bh = blockIdx.y;
    const int b  = bh >> 4, h = bh & 15;
    const int q0 = blockIdx.x * 128 + wid * 16;   // subtile u=0
    const int q1 = q0 + 64;                       // subtile u=1
    const int maskAll = flags[1];

    const bf16_t* Qp = Q  + (size_t)bh * SEQ * HEAD_DIM;
    const bf16_t* Kp = K  + (size_t)bh * SEQ * HEAD_DIM;
    const bf16_t* Vp = Vt + (size_t)bh * HEAD_DIM * SEQ;
    const int*    mp = mask + (size_t)b * SEQ * SEQ;

    bf16x8 qf[2][4];
    #pragma unroll
    for (int t = 0; t < 4; t++) {
        qf[0][t] = *(const bf16x8*)(Qp + (size_t)(q0 + l16) * HEAD_DIM + t * 32 + quad * 8);
        qf[1][t] = *(const bf16x8*)(Qp + (size_t)(q1 + l16) * HEAD_DIM + t * 32 + quad * 8);
    }

    bf16x8 onesf;
    #pragma unroll
    for (int u = 0; u < 8; u++) onesf[u] = (bf16_t)1.0f;

    const float CS = 0.1275260013f;  // (1/sqrt(128)) * log2(e)
    const float M0 = 16.0f;          // fixed softmax offset (exact; scale cancels)
    f32x4 l_acc[2] = {};             // O^T C-layout: all regs equal l[q=l16]
    f32x4 o_acc[2][8] = {};          // col = q = l16, row-of-tile dn: d = dn*16+quad*4+r

    auto stage = [&](int kt, int bb) {   // 8 loads/thread
        const int key0 = kt * 64;
        #pragma unroll
        for (int jj = 0; jj < 4; jj++) {
            int slot = jj * 256 + tid;
            int krow = slot & 63, k8 = slot >> 6;
            GLOAD16(Kp + (size_t)(key0 + krow) * HEAD_DIM + k8 * 8,
                    (bf16_t*)(&Ks[bb][0][0][0]) + slot * 8);
        }
        #pragma unroll
        for (int jj = 0; jj < 4; jj++) {
            int slot = jj * 256 + tid;
            int d = slot & 127, kq = slot >> 7;
            GLOAD16(Vp + (size_t)d * SEQ + key0 + kq * 8,
                    (bf16_t*)(&Vs[bb][0][0][0]) + slot * 8);
        }
    };

    const int NKT = SEQ / 64;

    auto abody = [&](int kt, int bb) {
        const int key0 = kt * 64;
        __syncthreads();                       // drains stage(kt); prev reads done
        if (kt + 1 < NKT) stage(kt + 1, bb ^ 1);

        // S = Q K^T for both q-subtiles; each kf register feeds 2 MFMAs
        f32x4 s0[4] = {}, s1[4] = {};
        #pragma unroll
        for (int nt = 0; nt < 4; nt++) {
            #pragma unroll
            for (int t = 0; t < 4; t++) {
                bf16x8 kf = *(const bf16x8*)(&Ks[bb][t * 4 + quad][nt * 16 + l16][0]);
                s0[nt] = MFMA16(qf[0][t], kf, s0[nt]);
                s1[nt] = MFMA16(qf[1][t], kf, s1[nt]);
            }
        }

        #pragma unroll
        for (int u = 0; u < 2; u++) {
            float p2[4][4];
            #pragma unroll
            for (int nt = 0; nt < 4; nt++)
                #pragma unroll
                for (int r = 0; r < 4; r++)
                    p2[nt][r] = (u ? s1[nt][r] : s0[nt][r]) * CS - M0;

            if (!maskAll) {
                int qb = u ? q1 : q0;
                #pragma unroll
                for (int nt = 0; nt < 4; nt++) {
                    int key = key0 + nt * 16 + l16;
                    #pragma unroll
                    for (int r = 0; r < 4; r++) {
                        int q = qb + quad * 4 + r;
                        if (mp[(size_t)q * SEQ + key] == 0) p2[nt][r] = -1e30f;
                    }
                }
            }

            // S C-layout -> per-wave LDS (Pl[q][key]) — same-wave roundtrip
            #pragma unroll
            for (int nt = 0; nt < 4; nt++)
                #pragma unroll
                for (int r = 0; r < 4; r++)
                    Pl[wid][quad * 4 + r][nt * 16 + l16] = (bf16_t)exp2f(p2[nt][r]);

            // O^T += V^T x P ; l = ones x P (B-operand P: n=q=l16, k=key)
            #pragma unroll
            for (int t = 0; t < 2; t++) {
                bf16x8 pf = *(const bf16x8*)(&Pl[wid][l16][t * 32 + quad * 8]);
                l_acc[u] = MFMA16(onesf, pf, l_acc[u]);
                #pragma unroll
                for (int dn = 0; dn < 8; dn++) {
                    bf16x8 vf = *(const bf16x8*)(&Vs[bb][t * 4 + quad][dn * 16 + l16][0]);
                    o_acc[u][dn] = MFMA16(vf, pf, o_acc[u][dn]);
                }
            }
        }
    };

    stage(0, 0);
    for (int base = 0; base < NKT; base += 2) {
        abody(base, 0);
        abody(base + 1, 1);
    }

    // epilogue: lane owns col q = qb + l16; rows d = dn*16 + quad*4 + r (r contig)
    #pragma unroll
    for (int u = 0; u < 2; u++) {
        int qb = u ? q1 : q0;
        float inv = 1.0f / l_acc[u][0];
        bf16_t* cp = ctx + ((size_t)(b * SEQ + qb + l16)) * H_DIM + h * HEAD_DIM;
        #pragma unroll
        for (int dn = 0; dn < 8; dn++) {
            bf16_t o4[4];
            #pragma unroll
            for (int r = 0; r < 4; r++) o4[r] = (bf16_t)(o_acc[u][dn][r] * inv);
            *(u64_t*)(cp + dn * 16 + quad * 4) = *(u64_t*)o4;
        }
    }
}

extern "C" void kernel_launch(void* const* d_in, const int* in_sizes, int n_in,
                              void* d_out, int out_size, void* d_ws, size_t ws_size,
                              hipStream_t stream) {
    const void* X    = d_in[0];
    const int*  mask = (const int*)d_in[1];
    const void* Wq   = d_in[2];
    const void* bq   = d_in[3];
    const void* Wk   = d_in[4];
    const void* bk   = d_in[5];
    const void* Wv   = d_in[6];
    const void* bv   = d_in[7];
    const void* Wo   = d_in[8];
    const void* bo   = d_in[9];

    const size_t NE = (size_t)BATCH * SEQ * H_DIM;   // 8388608
    const size_t NW = (size_t)H_DIM * H_DIM;         // 4194304

    int*    flags = (int*)d_ws;
    bf16_t* Xb    = (bf16_t*)((char*)d_ws + 256);
    bf16_t* Wts   = Xb + NE;        // 4 transposed weights [n][k]
    bf16_t* qws   = Wts + 4 * NW;   // [B,H,S,D]
    bf16_t* kws   = qws + NE;       // [B,H,S,D]
    bf16_t* vtws  = kws + NE;       // [B,H,D,S]
    bf16_t* cws   = vtws + NE;      // ctx [B,S,H*D]

    detect_kernel<<<1, 256, 0, stream>>>((const unsigned int*)X, flags);
    convert_mask_kernel<<<NE / (256 * 8), 256, 0, stream>>>(X, Xb, mask, flags);
    transpose_kernel<<<dim3(32, 32, 4), 256, 0, stream>>>(Wq, Wk, Wv, Wo, Wts, flags);
    gemm_qkv_kernel<<<1536, 256, 0, stream>>>(Xb, Wts, bq, bk, bv, qws, kws, vtws, flags);
    attn_kernel<<<dim3(SEQ / 128, BATCH * N_HEADS), 256, 0, stream>>>(
        qws, kws, vtws, mask, flags, cws);
    gemm_out_kernel<<<512, 256, 0, stream>>>(cws, Wts + 3 * NW, bo, d_out, flags);
}

// Round 11
// 570.870 us; speedup vs baseline: 1.0303x; 1.0303x over previous
//
#include <hip/hip_runtime.h>
#include <hip/hip_bf16.h>

#define H_DIM 2048
#define N_HEADS 16
#define HEAD_DIM 128
#define BATCH 2
#define SEQ 2048

typedef __bf16 bf16_t;
typedef __bf16 bf16x8 __attribute__((ext_vector_type(8)));
typedef float f32x4 __attribute__((ext_vector_type(4)));
typedef unsigned long long u64_t;

#define MFMA16(a, b, c) __builtin_amdgcn_mfma_f32_16x16x32_bf16((a), (b), (c), 0, 0, 0)

// async global->LDS, 16 B per lane. LDS side must be uniform-base + lane*16.
#define GLOAD16(gp, lp) __builtin_amdgcn_global_load_lds( \
    (const __attribute__((address_space(1))) void*)(gp),  \
    (__attribute__((address_space(3))) void*)(lp), 16, 0, 0)

// raw barrier / waitcnt (R7 gemm pipeline — best measured)
#define WAIT_VM6()  asm volatile("s_waitcnt vmcnt(6)" ::: "memory")
#define WAIT_VM4()  asm volatile("s_waitcnt vmcnt(4)" ::: "memory")
#define WAIT_VM0()  asm volatile("s_waitcnt vmcnt(0)" ::: "memory")
#define RAW_BARRIER() asm volatile("s_barrier" ::: "memory")

// flags[0] = inputs stored as bf16 (1) or fp32 (0); flags[1] = mask all-ones
__global__ __launch_bounds__(256) void detect_kernel(const unsigned int* __restrict__ X,
                                                     int* __restrict__ flags) {
    __shared__ int cnt[256];
    int t = threadIdx.x;
    int c = 0;
    for (int i = 0; i < 16; i++) {
        unsigned w  = X[t * 16 + i];
        unsigned lo = w & 0xFFFFu;
        unsigned e  = (lo >> 7) & 0xFFu;
        if (lo == 0u || (e >= 100u && e <= 141u)) c++;
    }
    cnt[t] = c;
    __syncthreads();
    for (int s = 128; s > 0; s >>= 1) {
        if (t < s) cnt[t] += cnt[t + s];
        __syncthreads();
    }
    if (t == 0) { flags[0] = (cnt[0] >= 2048) ? 1 : 0; flags[1] = 1; }
}

__device__ inline bf16x8 load8(const void* __restrict__ p, size_t idx, int isbf16) {
    if (isbf16) {
        return *(const bf16x8*)((const bf16_t*)p + idx);
    } else {
        const float* f = (const float*)p + idx;
        float4 a = *(const float4*)f;
        float4 b = *(const float4*)(f + 4);
        bf16x8 r;
        r[0] = (bf16_t)a.x; r[1] = (bf16_t)a.y; r[2] = (bf16_t)a.z; r[3] = (bf16_t)a.w;
        r[4] = (bf16_t)b.x; r[5] = (bf16_t)b.y; r[6] = (bf16_t)b.z; r[7] = (bf16_t)b.w;
        return r;
    }
}

__device__ inline float readf(const void* __restrict__ p, int idx, int isbf16) {
    return isbf16 ? (float)((const bf16_t*)p)[idx] : ((const float*)p)[idx];
}

// Fused preprocessing, grid 8192:
//  blocks [0,4096):    X -> Xb (bf16) + mask all-ones check (8 elems/thread)
//  blocks [4096,8192): Wt[z][n][k] = W_z[k][n] transpose, 64x64 LDS tiles
__global__ __launch_bounds__(256) void prep_kernel(
    const void* __restrict__ X, bf16_t* __restrict__ Xb,
    const int* __restrict__ mask,
    const void* __restrict__ W0, const void* __restrict__ W1,
    const void* __restrict__ W2, const void* __restrict__ W3,
    bf16_t* __restrict__ Wts, int* __restrict__ flags)
{
    const int isbf16 = flags[0];
    const int tid = threadIdx.x;

    if (blockIdx.x < 4096) {
        size_t i = ((size_t)blockIdx.x * 256 + tid) * 8;
        bf16x8 v = load8(X, i, isbf16);
        *(bf16x8*)(Xb + i) = v;

        const int4* p = (const int4*)(mask + i);
        int4 a = p[0], b = p[1];
        int all = (a.x != 0) & (a.y != 0) & (a.z != 0) & (a.w != 0) &
                  (b.x != 0) & (b.y != 0) & (b.z != 0) & (b.w != 0);
        if (!all) atomicAnd(&flags[1], 0);
    } else {
        const int t   = blockIdx.x - 4096;
        const int z   = t >> 10;
        const int rem = t & 1023;
        const int n0  = (rem & 31) * 64;
        const int k0  = (rem >> 5) * 64;
        const void* W = (z == 0) ? W0 : (z == 1) ? W1 : (z == 2) ? W2 : W3;
        bf16_t* out = Wts + (size_t)z * H_DIM * H_DIM;

        __shared__ __attribute__((aligned(16))) bf16_t Ts[64][72];
        #pragma unroll
        for (int j = 0; j < 2; j++) {
            int idx = j * 2048 + tid * 8;
            int r = idx >> 6, c = idx & 63;
            bf16x8 v = load8(W, (size_t)(k0 + r) * H_DIM + n0 + c, isbf16);
            *(bf16x8*)(&Ts[r][c]) = v;
        }
        __syncthreads();
        const int wr = tid & 63;
        const int wcg = (tid >> 6) * 8;
        #pragma unroll
        for (int j = 0; j < 2; j++) {
            int wc = wcg + j * 32;
            bf16x8 o;
            #pragma unroll
            for (int u = 0; u < 8; u++) o[u] = Ts[wc + u][wr];
            *(bf16x8*)(&out[(size_t)(n0 + wr) * H_DIM + k0 + wc]) = o;
        }
    }
}

// 256x128 GEMM, triple-buffered prefetch-dist-2, XCD-swizzled grid(768).
// (R7 structure — best measured across 7 variants: 227 us)
// z=0,1: scatter [B,H,S,D] (Q,K). z=2: scatter V^T [B,H,D,S].
__global__ __launch_bounds__(256, 2) void gemm_qkv_kernel(
    const bf16_t* __restrict__ A, const bf16_t* __restrict__ Wts,
    const void* __restrict__ b0, const void* __restrict__ b1, const void* __restrict__ b2,
    bf16_t* __restrict__ qws, bf16_t* __restrict__ kws, bf16_t* __restrict__ vtws,
    const int* __restrict__ flags)
{
    const int isbf16 = flags[0];
    const int L    = blockIdx.x;
    const int xcd  = L & 7;
    const int j    = L >> 3;              // 0..95
    const int c    = xcd * 6 + (j % 6);   // 0..47 = z*16 + ncol
    const int mrow = j / 6;               // 0..15
    const int z    = c >> 4;
    const int m0   = mrow * 256;
    const int n0   = (c & 15) * 128;

    const bf16_t* Wt = Wts + (size_t)z * H_DIM * H_DIM;
    const void* bias = (z == 0) ? b0 : (z == 1) ? b1 : b2;
    bf16_t* dst = (z == 0) ? qws : (z == 1) ? kws : vtws;

    __shared__ __attribute__((aligned(16))) bf16_t As[3][4][256][8];  // 3 x 16 KB
    __shared__ __attribute__((aligned(16))) bf16_t Bs[3][4][128][8];  // 3 x  8 KB

    const int tid  = threadIdx.x;
    const int lane = tid & 63;
    const int wid  = tid >> 6;
    const int quad = lane >> 4;
    const int l16  = lane & 15;
    const int wm   = (wid >> 1) * 128;
    const int wn   = (wid & 1) * 64;

    f32x4 acc[8][4] = {};

    auto stage = [&](int k0, int sb) {   // 6 loads/thread: 4 A + 2 B
        #pragma unroll
        for (int jj = 0; jj < 4; jj++) {
            int slot = jj * 256 + tid;
            int k8 = slot >> 8, row = slot & 255;
            GLOAD16(A + (size_t)(m0 + row) * H_DIM + k0 + k8 * 8,
                    (bf16_t*)(&As[sb][0][0][0]) + slot * 8);
        }
        #pragma unroll
        for (int jj = 0; jj < 2; jj++) {
            int slot = jj * 256 + tid;
            int k8 = slot >> 7, row = slot & 127;
            GLOAD16(Wt + (size_t)(n0 + row) * H_DIM + k0 + k8 * 8,
                    (bf16_t*)(&Bs[sb][0][0][0]) + slot * 8);
        }
    };

    auto body = [&](int it, int bb, int sb, int mode) {
        if (mode == 2) { WAIT_VM0(); } else { WAIT_VM6(); }
        RAW_BARRIER();
        if (mode == 0) stage((it + 2) * 32, sb);
        bf16x8 bfr[4];
        #pragma unroll
        for (int i = 0; i < 4; i++)
            bfr[i] = *(const bf16x8*)(&Bs[bb][quad][wn + i * 16 + l16][0]);
        #pragma unroll
        for (int mi = 0; mi < 8; mi++) {
            bf16x8 af = *(const bf16x8*)(&As[bb][quad][wm + mi * 16 + l16][0]);
            #pragma unroll
            for (int ni = 0; ni < 4; ni++)
                acc[mi][ni] = MFMA16(af, bfr[ni], acc[mi][ni]);
        }
    };

    stage(0, 0);
    stage(32, 1);
    for (int base = 0; base < 60; base += 3) {
        body(base,     0, 2, 0);
        body(base + 1, 1, 0, 0);
        body(base + 2, 2, 1, 0);
    }
    body(60, 0, 2, 0);
    body(61, 1, 0, 0);
    body(62, 2, 1, 1);
    body(63, 0, 0, 2);

    // C/D layout: col = lane&15, row = quad*4 + reg
    #pragma unroll
    for (int ni = 0; ni < 4; ni++) {
        int col = n0 + wn + ni * 16 + l16;
        int h = col >> 7, d = col & (HEAD_DIM - 1);
        float bv = readf(bias, col, isbf16);
        #pragma unroll
        for (int mi = 0; mi < 8; mi++) {
            int row0 = m0 + wm + mi * 16 + quad * 4;
            int b = row0 >> 11;
            if (z < 2) {
                #pragma unroll
                for (int r = 0; r < 4; r++) {
                    int s = (row0 + r) & (SEQ - 1);
                    dst[((size_t)(b * N_HEADS + h) * SEQ + s) * HEAD_DIM + d] =
                        (bf16_t)(acc[mi][ni][r] + bv);
                }
            } else {
                int s0 = row0 & (SEQ - 1);
                bf16_t o[4];
                #pragma unroll
                for (int r = 0; r < 4; r++) o[r] = (bf16_t)(acc[mi][ni][r] + bv);
                *(u64_t*)(&dst[((size_t)(b * N_HEADS + h) * HEAD_DIM + d) * SEQ + s0]) =
                    *(u64_t*)o;
            }
        }
    }
}

// out-projection, 128x128 triple-buffer dist-2 (R7 best). grid(512).
__global__ __launch_bounds__(256) void gemm_out_kernel(
    const bf16_t* __restrict__ A, const bf16_t* __restrict__ Wt,
    const void* __restrict__ bias, void* __restrict__ C,
    const int* __restrict__ flags)
{
    const int isbf16 = flags[0];
    const int L    = blockIdx.x;
    const int xcd  = L & 7;
    const int j    = L >> 3;              // 0..63
    const int m0   = (j >> 1) * 128;
    const int n0   = (xcd * 2 + (j & 1)) * 128;

    __shared__ __attribute__((aligned(16))) bf16_t As[3][4][128][8];
    __shared__ __attribute__((aligned(16))) bf16_t Bs[3][4][128][8];

    const int tid  = threadIdx.x;
    const int lane = tid & 63;
    const int wid  = tid >> 6;
    const int quad = lane >> 4;
    const int l16  = lane & 15;
    const int wm   = (wid >> 1) * 64;
    const int wn   = (wid & 1) * 64;

    f32x4 acc[4][4] = {};

    auto stage = [&](int k0, int sb) {
        #pragma unroll
        for (int jj = 0; jj < 2; jj++) {
            int slot = jj * 256 + tid;
            int k8 = slot >> 7, row = slot & 127;
            GLOAD16(A  + (size_t)(m0 + row) * H_DIM + k0 + k8 * 8,
                    (bf16_t*)(&As[sb][0][0][0]) + slot * 8);
            GLOAD16(Wt + (size_t)(n0 + row) * H_DIM + k0 + k8 * 8,
                    (bf16_t*)(&Bs[sb][0][0][0]) + slot * 8);
        }
    };

    auto body = [&](int it, int bb, int sb, int mode) {
        if (mode == 2) { WAIT_VM0(); } else { WAIT_VM4(); }
        RAW_BARRIER();
        if (mode == 0) stage((it + 2) * 32, sb);
        bf16x8 af[4], bfr[4];
        #pragma unroll
        for (int i = 0; i < 4; i++) {
            af[i]  = *(const bf16x8*)(&As[bb][quad][wm + i * 16 + l16][0]);
            bfr[i] = *(const bf16x8*)(&Bs[bb][quad][wn + i * 16 + l16][0]);
        }
        #pragma unroll
        for (int mi = 0; mi < 4; mi++)
            #pragma unroll
            for (int ni = 0; ni < 4; ni++)
                acc[mi][ni] = MFMA16(af[mi], bfr[ni], acc[mi][ni]);
    };

    stage(0, 0);
    stage(32, 1);
    for (int base = 0; base < 60; base += 3) {
        body(base,     0, 2, 0);
        body(base + 1, 1, 0, 0);
        body(base + 2, 2, 1, 0);
    }
    body(60, 0, 2, 0);
    body(61, 1, 0, 0);
    body(62, 2, 1, 1);
    body(63, 0, 0, 2);

    #pragma unroll
    for (int ni = 0; ni < 4; ni++) {
        int col = n0 + wn + ni * 16 + l16;
        float bv = readf(bias, col, isbf16);
        #pragma unroll
        for (int mi = 0; mi < 4; mi++) {
            int row0 = m0 + wm + mi * 16 + quad * 4;
            #pragma unroll
            for (int r = 0; r < 4; r++) {
                float v = acc[mi][ni][r] + bv;
                if (isbf16) ((bf16_t*)C)[(size_t)(row0 + r) * H_DIM + col] = (bf16_t)v;
                else        ((float*)C)[(size_t)(row0 + r) * H_DIM + col]  = v;
            }
        }
    }
}

// Flash attention, dual-Q, fixed-offset softmax, O^T = V^T x P (R10, neutral-best).
__global__ __launch_bounds__(256, 2) void attn_kernel(
    const bf16_t* __restrict__ Q, const bf16_t* __restrict__ K,
    const bf16_t* __restrict__ Vt, const int* __restrict__ mask,
    const int* __restrict__ flags, bf16_t* __restrict__ ctx)
{
    __shared__ __attribute__((aligned(16))) bf16_t Ks[2][16][64][8];  // 32 KB
    __shared__ __attribute__((aligned(16))) bf16_t Vs[2][8][128][8];  // 32 KB
    __shared__ __attribute__((aligned(16))) bf16_t Pl[4][16][72];     // 9 KB, per-wave

    const int tid  = threadIdx.x;
    const int lane = tid & 63;
    const int wid  = tid >> 6;
    const int quad = lane >> 4;
    const int l16  = lane & 15;

    const int bh = blockIdx.y;
    const int b  = bh >> 4, h = bh & 15;
    const int q0 = blockIdx.x * 128 + wid * 16;   // subtile u=0
    const int q1 = q0 + 64;                       // subtile u=1
    const int maskAll = flags[1];

    const bf16_t* Qp = Q  + (size_t)bh * SEQ * HEAD_DIM;
    const bf16_t* Kp = K  + (size_t)bh * SEQ * HEAD_DIM;
    const bf16_t* Vp = Vt + (size_t)bh * HEAD_DIM * SEQ;
    const int*    mp = mask + (size_t)b * SEQ * SEQ;

    bf16x8 qf[2][4];
    #pragma unroll
    for (int t = 0; t < 4; t++) {
        qf[0][t] = *(const bf16x8*)(Qp + (size_t)(q0 + l16) * HEAD_DIM + t * 32 + quad * 8);
        qf[1][t] = *(const bf16x8*)(Qp + (size_t)(q1 + l16) * HEAD_DIM + t * 32 + quad * 8);
    }

    bf16x8 onesf;
    #pragma unroll
    for (int u = 0; u < 8; u++) onesf[u] = (bf16_t)1.0f;

    const float CS = 0.1275260013f;  // (1/sqrt(128)) * log2(e)
    const float M0 = 16.0f;          // fixed softmax offset (exact; scale cancels)
    f32x4 l_acc[2] = {};
    f32x4 o_acc[2][8] = {};

    auto stage = [&](int kt, int bb) {   // 8 loads/thread
        const int key0 = kt * 64;
        #pragma unroll
        for (int jj = 0; jj < 4; jj++) {
            int slot = jj * 256 + tid;
            int krow = slot & 63, k8 = slot >> 6;
            GLOAD16(Kp + (size_t)(key0 + krow) * HEAD_DIM + k8 * 8,
                    (bf16_t*)(&Ks[bb][0][0][0]) + slot * 8);
        }
        #pragma unroll
        for (int jj = 0; jj < 4; jj++) {
            int slot = jj * 256 + tid;
            int d = slot & 127, kq = slot >> 7;
            GLOAD16(Vp + (size_t)d * SEQ + key0 + kq * 8,
                    (bf16_t*)(&Vs[bb][0][0][0]) + slot * 8);
        }
    };

    const int NKT = SEQ / 64;

    auto abody = [&](int kt, int bb) {
        const int key0 = kt * 64;
        __syncthreads();                       // drains stage(kt); prev reads done
        if (kt + 1 < NKT) stage(kt + 1, bb ^ 1);

        f32x4 s0[4] = {}, s1[4] = {};
        #pragma unroll
        for (int nt = 0; nt < 4; nt++) {
            #pragma unroll
            for (int t = 0; t < 4; t++) {
                bf16x8 kf = *(const bf16x8*)(&Ks[bb][t * 4 + quad][nt * 16 + l16][0]);
                s0[nt] = MFMA16(qf[0][t], kf, s0[nt]);
                s1[nt] = MFMA16(qf[1][t], kf, s1[nt]);
            }
        }

        #pragma unroll
        for (int u = 0; u < 2; u++) {
            float p2[4][4];
            #pragma unroll
            for (int nt = 0; nt < 4; nt++)
                #pragma unroll
                for (int r = 0; r < 4; r++)
                    p2[nt][r] = (u ? s1[nt][r] : s0[nt][r]) * CS - M0;

            if (!maskAll) {
                int qb = u ? q1 : q0;
                #pragma unroll
                for (int nt = 0; nt < 4; nt++) {
                    int key = key0 + nt * 16 + l16;
                    #pragma unroll
                    for (int r = 0; r < 4; r++) {
                        int q = qb + quad * 4 + r;
                        if (mp[(size_t)q * SEQ + key] == 0) p2[nt][r] = -1e30f;
                    }
                }
            }

            #pragma unroll
            for (int nt = 0; nt < 4; nt++)
                #pragma unroll
                for (int r = 0; r < 4; r++)
                    Pl[wid][quad * 4 + r][nt * 16 + l16] = (bf16_t)exp2f(p2[nt][r]);

            #pragma unroll
            for (int t = 0; t < 2; t++) {
                bf16x8 pf = *(const bf16x8*)(&Pl[wid][l16][t * 32 + quad * 8]);
                l_acc[u] = MFMA16(onesf, pf, l_acc[u]);
                #pragma unroll
                for (int dn = 0; dn < 8; dn++) {
                    bf16x8 vf = *(const bf16x8*)(&Vs[bb][t * 4 + quad][dn * 16 + l16][0]);
                    o_acc[u][dn] = MFMA16(vf, pf, o_acc[u][dn]);
                }
            }
        }
    };

    stage(0, 0);
    for (int base = 0; base < NKT; base += 2) {
        abody(base, 0);
        abody(base + 1, 1);
    }

    #pragma unroll
    for (int u = 0; u < 2; u++) {
        int qb = u ? q1 : q0;
        float inv = 1.0f / l_acc[u][0];
        bf16_t* cp = ctx + ((size_t)(b * SEQ + qb + l16)) * H_DIM + h * HEAD_DIM;
        #pragma unroll
        for (int dn = 0; dn < 8; dn++) {
            bf16_t o4[4];
            #pragma unroll
            for (int r = 0; r < 4; r++) o4[r] = (bf16_t)(o_acc[u][dn][r] * inv);
            *(u64_t*)(cp + dn * 16 + quad * 4) = *(u64_t*)o4;
        }
    }
}

extern "C" void kernel_launch(void* const* d_in, const int* in_sizes, int n_in,
                              void* d_out, int out_size, void* d_ws, size_t ws_size,
                              hipStream_t stream) {
    const void* X    = d_in[0];
    const int*  mask = (const int*)d_in[1];
    const void* Wq   = d_in[2];
    const void* bq   = d_in[3];
    const void* Wk   = d_in[4];
    const void* bk   = d_in[5];
    const void* Wv   = d_in[6];
    const void* bv   = d_in[7];
    const void* Wo   = d_in[8];
    const void* bo   = d_in[9];

    const size_t NE = (size_t)BATCH * SEQ * H_DIM;   // 8388608
    const size_t NW = (size_t)H_DIM * H_DIM;         // 4194304

    int*    flags = (int*)d_ws;
    bf16_t* Xb    = (bf16_t*)((char*)d_ws + 256);
    bf16_t* Wts   = Xb + NE;        // 4 transposed weights [n][k]
    bf16_t* qws   = Wts + 4 * NW;   // [B,H,S,D]
    bf16_t* kws   = qws + NE;       // [B,H,S,D]
    bf16_t* vtws  = kws + NE;       // [B,H,D,S]
    bf16_t* cws   = vtws + NE;      // ctx [B,S,H*D]

    detect_kernel<<<1, 256, 0, stream>>>((const unsigned int*)X, flags);
    prep_kernel<<<8192, 256, 0, stream>>>(X, Xb, mask, Wq, Wk, Wv, Wo, Wts, flags);
    gemm_qkv_kernel<<<768, 256, 0, stream>>>(Xb, Wts, bq, bk, bv, qws, kws, vtws, flags);
    attn_kernel<<<dim3(SEQ / 128, BATCH * N_HEADS), 256, 0, stream>>>(
        qws, kws, vtws, mask, flags, cws);
    gemm_out_kernel<<<512, 256, 0, stream>>>(cws, Wts + 3 * NW, bo, d_out, flags);
}